// Round 2
// baseline (1463.094 us; speedup 1.0000x reference)
//
#include <hip/hip_runtime.h>
#include <hip/hip_bf16.h>
#include <stdint.h>

#define NC 8192
#define GG 512

typedef __attribute__((ext_vector_type(8))) short bf16x8;   // 8 bf16 = 4 VGPRs (MFMA A/B frag)
typedef __attribute__((ext_vector_type(4))) float fx4;      // MFMA C/D frag

__device__ __forceinline__ float bf2f(short s){
  union { uint32_t u; float f; } c; c.u = ((uint32_t)(uint16_t)s) << 16; return c.f;
}
__device__ __forceinline__ short f2bf(float f){
  union { float f; uint32_t u; } c; c.f = f;
  uint32_t u = c.u;
  uint32_t r = (u + 0x7fffu + ((u >> 16) & 1u)) >> 16;   // RNE
  return (short)(uint16_t)r;
}
__device__ __forceinline__ void g2l16(const void* g, void* l){
  __builtin_amdgcn_global_load_lds((const __attribute__((address_space(1))) void*)g,
                                   (__attribute__((address_space(3))) void*)l, 16, 0, 0);
}

// ---------------- elementwise casts ----------------
__global__ void cast_f32_bf16(const float* __restrict__ in, short* __restrict__ out, int n){
  int i = (blockIdx.x * 256 + threadIdx.x) * 4;
  if (i < n){
    float4 v = *(const float4*)(in + i);
    uint32_t lo = (uint32_t)(uint16_t)f2bf(v.x) | ((uint32_t)(uint16_t)f2bf(v.y) << 16);
    uint32_t hi = (uint32_t)(uint16_t)f2bf(v.z) | ((uint32_t)(uint16_t)f2bf(v.w) << 16);
    *(uint2*)(out + i) = make_uint2(lo, hi);
  }
}

// in f32 [R][C] -> out bf16 at out[(c)*ostride + roff + r]  (transpose + cast)
__global__ void transpose_cast(const float* __restrict__ in, short* __restrict__ out,
                               int R, int C, int ostride, int roff){
  __shared__ float t[32][33];
  int c0 = blockIdx.x * 32, r0 = blockIdx.y * 32;
  int x = threadIdx.x & 31, y = threadIdx.x >> 5;  // y in 0..7
  #pragma unroll
  for (int it = 0; it < 4; ++it)
    t[y + 8*it][x] = in[(size_t)(r0 + y + 8*it) * C + c0 + x];
  __syncthreads();
  #pragma unroll
  for (int it = 0; it < 4; ++it)
    out[(size_t)(c0 + y + 8*it) * ostride + roff + r0 + x] = f2bf(t[x][y + 8*it]);
}

// ---------------- main GEMM: C[M][N] = A[M][K] @ B[N][K]^T ----------------
// BM=128 BN=128 BK=64, 4 waves as 2x2 of [64m x 64n], 16x16x32 bf16 MFMA.
// modes: 0 = outb = bf16(tanh(c+bias))
//        1 = outf = c+bias+res  (f32)
//        3 = outf += scale*c
//        5 = v = c / res[m]; outf = v; ((float*)outb) = v   (dual f32 write)
//        6 = outb = bf16(scale*c)
// LDS rows are 128B (BK*2) => XOR-swizzle column chunks by (row&7) so ds_read_b128
// across 16 lanes is 2-way (free). Swizzle applied to GLOBAL address at staging
// (keeps lds dst = wave-uniform base + lane*16, required by global_load_lds).
__global__ __launch_bounds__(256, 2)
void gemm_bt(const short* __restrict__ A, int lda, const short* __restrict__ B, int ldb,
             int K, int mode, const float* __restrict__ bias,
             const float* __restrict__ res, int ldres,
             float* __restrict__ outf, short* __restrict__ outb, int ldo, float scale)
{
  __shared__ __align__(16) short As[128 * 64];
  __shared__ __align__(16) short Bs[128 * 64];
  const int tid = threadIdx.x;
  const int lane = tid & 63, wave = tid >> 6;
  const int wm = wave >> 1, wn = wave & 1;
  const int l16 = lane & 15, q = lane >> 4;
  const size_t i0 = (size_t)blockIdx.y * 128;
  const int n0 = blockIdx.x * 128;
  fx4 acc[4][4] = {};

  for (int k0 = 0; k0 < K; k0 += 64){
    #pragma unroll
    for (int inst = 0; inst < 4; ++inst){              // A tile 128x64 bf16 = 16KB
      int ch = inst * 256 + tid;
      int r = ch >> 3, pc = ch & 7;
      int colc = (pc ^ (r & 7)) * 8;
      g2l16(A + (i0 + r) * (size_t)lda + k0 + colc, As + ch * 8);
    }
    #pragma unroll
    for (int inst = 0; inst < 4; ++inst){              // B tile 128x64 bf16 = 16KB
      int ch = inst * 256 + tid;
      int r = ch >> 3, pc = ch & 7;
      int colc = (pc ^ (r & 7)) * 8;
      g2l16(B + (size_t)(n0 + r) * (size_t)ldb + k0 + colc, Bs + ch * 8);
    }
    __syncthreads();
    #pragma unroll
    for (int ks = 0; ks < 2; ++ks){
      int k8 = ks * 4 + q;
      bf16x8 af[4], bfr[4];
      #pragma unroll
      for (int mi = 0; mi < 4; ++mi){
        int r = wm * 64 + mi * 16 + l16;
        af[mi] = *(const bf16x8*)(As + r * 64 + ((k8 ^ (r & 7)) << 3));
      }
      #pragma unroll
      for (int ni = 0; ni < 4; ++ni){
        int r = wn * 64 + ni * 16 + l16;
        bfr[ni] = *(const bf16x8*)(Bs + r * 64 + ((k8 ^ (r & 7)) << 3));
      }
      #pragma unroll
      for (int mi = 0; mi < 4; ++mi)
        #pragma unroll
        for (int ni = 0; ni < 4; ++ni)
          acc[mi][ni] = __builtin_amdgcn_mfma_f32_16x16x32_bf16(af[mi], bfr[ni], acc[mi][ni], 0, 0, 0);
    }
    __syncthreads();
  }
  // epilogue: C frag layout col=lane&15 (n), row=q*4+r (m)  [verified R1]
  #pragma unroll
  for (int mi = 0; mi < 4; ++mi){
    #pragma unroll
    for (int ni = 0; ni < 4; ++ni){
      int n = n0 + wn * 64 + ni * 16 + l16;
      float b = bias ? bias[n] : 0.0f;
      #pragma unroll
      for (int r = 0; r < 4; ++r){
        size_t m = i0 + wm * 64 + mi * 16 + q * 4 + r;
        float v = acc[mi][ni][r];
        size_t o = m * (size_t)ldo + n;
        if (mode == 0)      outb[o] = f2bf(tanhf(v + b));
        else if (mode == 1) outf[o] = v + b + res[m * (size_t)ldres + n];
        else if (mode == 3) outf[o] += v * scale;
        else if (mode == 5){ float vv = v / res[m]; outf[o] = vv; ((float*)outb)[o] = vv; }
        else                outb[o] = f2bf(v * scale);   // mode 6
      }
    }
  }
}

// ---------------- score kernel: P[i][j] bf16, full 8192-wide panel ----------------
// mode 0 (smooth): p = E[j]*exp(-sqrt(max(sq_i+sq_j-2*enc_i.enc_j,0))), l[i] += p
// mode 1 (sig):    p = sigmoid(Ah[i].enc[j])
// Each block: 32 i-rows x 1024 j-cols (loop of 8 x 128j, wave covers 32j).
__global__ __launch_bounds__(256, 4)
void score_kernel(const short* __restrict__ encJ, const short* __restrict__ Bi,
                  const float* __restrict__ sq, const float* __restrict__ E,
                  float* __restrict__ l, short* __restrict__ P, int mode)
{
  const int tid = threadIdx.x, lane = tid & 63, wave = tid >> 6;
  const int l16 = lane & 15, q = lane >> 4;
  const int i0 = blockIdx.y * 32;
  const int jblk = blockIdx.x * 1024;

  bf16x8 bfr[2];
  #pragma unroll
  for (int nf = 0; nf < 2; ++nf)
    bfr[nf] = *(const bf16x8*)(Bi + (size_t)(i0 + nf * 16 + l16) * 32 + q * 8);
  float sqi[2] = {0.f, 0.f};
  if (mode == 0){ sqi[0] = sq[i0 + l16]; sqi[1] = sq[i0 + 16 + l16]; }
  float lacc[2] = {0.f, 0.f};

  for (int jj = 0; jj < 1024; jj += 128){
    const int jg0 = jblk + jj + wave * 32;
    #pragma unroll
    for (int mf = 0; mf < 2; ++mf){
      bf16x8 af = *(const bf16x8*)(encJ + (size_t)(jg0 + mf * 16 + l16) * 32 + q * 8);
      float4 sqj = make_float4(0,0,0,0), Ej = make_float4(0,0,0,0);
      if (mode == 0){
        sqj = *(const float4*)(sq + jg0 + mf * 16 + q * 4);
        Ej  = *(const float4*)(E  + jg0 + mf * 16 + q * 4);
      }
      #pragma unroll
      for (int nf = 0; nf < 2; ++nf){
        fx4 c = {};
        c = __builtin_amdgcn_mfma_f32_16x16x32_bf16(af, bfr[nf], c, 0, 0, 0);
        float pv[4];
        #pragma unroll
        for (int r = 0; r < 4; ++r){
          float dot = c[r];
          if (mode == 0){
            float sj = ((const float*)&sqj)[r];
            float ej = ((const float*)&Ej)[r];
            float d2 = fmaxf(sqi[nf] + sj - 2.0f * dot, 0.0f);
            float p = ej * __expf(-sqrtf(d2));
            lacc[nf] += p;
            pv[r] = p;
          } else {
            pv[r] = 1.0f / (1.0f + __expf(-dot));
          }
        }
        uint32_t lo = (uint32_t)(uint16_t)f2bf(pv[0]) | ((uint32_t)(uint16_t)f2bf(pv[1]) << 16);
        uint32_t hi = (uint32_t)(uint16_t)f2bf(pv[2]) | ((uint32_t)(uint16_t)f2bf(pv[3]) << 16);
        size_t iG = i0 + nf * 16 + l16;
        *(uint2*)(P + iG * (size_t)NC + jg0 + mf * 16 + q * 4) = make_uint2(lo, hi);
      }
    }
  }
  if (mode == 0){
    #pragma unroll
    for (int nf = 0; nf < 2; ++nf){
      float v = lacc[nf];
      v += __shfl_xor(v, 16);
      v += __shfl_xor(v, 32);
      if (lane < 16) atomicAdd(l + i0 + nf * 16 + lane, v);
    }
  }
}

// ---------------- small MLP tails ----------------
__global__ void embed2_kernel(const short* __restrict__ H2, const float* __restrict__ eW2,
                              const float* __restrict__ eb2, const float* __restrict__ T4,
                              short* __restrict__ encb, float* __restrict__ sq,
                              short* __restrict__ Ah)
{
  __shared__ float encS[8][32];
  int d = threadIdx.x & 31, cl = threadIdx.x >> 5;
  size_t c = (size_t)blockIdx.x * 8 + cl;
  float s = eb2[d];
  const short* hrow = H2 + c * 256;
  for (int k = 0; k < 256; ++k) s += bf2f(hrow[k]) * eW2[k * 32 + d];
  short eb = f2bf(s);
  encb[c * 32 + d] = eb;
  encS[cl][d] = bf2f(eb);
  __syncthreads();
  if (d == 0){
    float t = 0;
    for (int k = 0; k < 32; ++k) t += encS[cl][k] * encS[cl][k];
    sq[c] = t;
  }
  #pragma unroll
  for (int h = 0; h < 4; ++h){
    float a = 0;
    const float* T = T4 + h * 1024;
    for (int k = 0; k < 32; ++k) a += encS[cl][k] * T[k * 32 + d];
    Ah[(size_t)h * NC * 32 + c * 32 + d] = f2bf(a);
  }
}

__global__ void quality_kernel(const float* __restrict__ X, const float* __restrict__ qW1,
                               const float* __restrict__ qb1, const float* __restrict__ qW2,
                               const float* __restrict__ qb2, float* __restrict__ E)
{
  int j = threadIdx.x & 63, cl = threadIdx.x >> 6;
  size_t c = (size_t)blockIdx.x * 4 + cl;
  float s = qb1[j];
  const float* xr = X + c * 512;
  for (int k = 0; k < 512; ++k) s += xr[k] * qW1[k * 64 + j];
  float t = tanhf(s) * qW2[j];
  #pragma unroll
  for (int o = 32; o >= 1; o >>= 1) t += __shfl_xor(t, o);
  if (j == 0) E[c] = __expf(t + qb2[0]);
}

// ---------------- host ----------------
extern "C" void kernel_launch(void* const* d_in, const int* in_sizes, int n_in,
                              void* d_out, int out_size, void* d_ws, size_t ws_size,
                              hipStream_t stream)
{
  const float* raw = (const float*)d_in[0];
  const float* dW1 = (const float*)d_in[1];
  const float* db1 = (const float*)d_in[2];
  const float* dW2 = (const float*)d_in[3];
  const float* db2 = (const float*)d_in[4];
  const float* eW1 = (const float*)d_in[5];
  const float* eb1 = (const float*)d_in[6];
  const float* eW2 = (const float*)d_in[7];
  const float* eb2 = (const float*)d_in[8];
  const float* qW1 = (const float*)d_in[9];
  const float* qb1 = (const float*)d_in[10];
  const float* qW2 = (const float*)d_in[11];
  const float* qb2 = (const float*)d_in[12];
  const float* Tr  = (const float*)d_in[13];
  const float* Gr  = (const float*)d_in[14];

  float* outD = (float*)d_out;                    // denoised [8192][512]
  float* outS = outD + (size_t)NC * GG;           // smoothed
  float* outF = outS + (size_t)NC * GG;           // final

  char* ws = (char*)d_ws;
  size_t off = 0;
  auto take = [&](size_t bytes) -> char* {
    char* p = ws + off; off += (bytes + 255) & ~(size_t)255; return p;
  };
  // persistent region
  short* GTc  = (short*)take((size_t)512 * 2048 * 2);     // gene_responses^T concat [n][4*512]
  short* encb = (short*)take((size_t)NC * 32 * 2);
  short* Ahb  = (short*)take((size_t)4 * NC * 32 * 2);
  float* sqv  = (float*)take((size_t)NC * 4);
  float* Ev   = (float*)take((size_t)NC * 4);
  float* lv   = (float*)take((size_t)NC * 4);
  short* smoT = (short*)take((size_t)GG * NC * 2);        // smoothed^T [g][cell]
  // overlay region: early temporaries vs Ucat (dead before Ucat is written)
  char* overlay = take((size_t)NC * 2048 * 2);            // 33.5 MB
  short* Ucat = (short*)overlay;                          // [8192][4*512] bf16 head outputs
  short* Xb   = (short*)overlay;                              // raw bf16 [cell][g]  (8 MB)
  short* dW1T = (short*)(overlay + (8u << 20));
  short* dW2T = (short*)(overlay + (8u << 20) + (512*512*2));
  short* eW1T = (short*)(overlay + (8u << 20) + 2*(512*512*2));
  short* Hb   = (short*)(overlay + (10u << 20));              // hidden bf16 (8 MB)
  short* denT = (short*)(overlay + (18u << 20));              // denoised^T (8 MB)
  short* Pbuf = (short*)take((size_t)NC * NC * 2);        // 134 MB

  dim3 b256(256);
  // ---- casts / transposed weights ----
  cast_f32_bf16<<<dim3((NC * GG) / 1024), b256, 0, stream>>>(raw, Xb, NC * GG);
  transpose_cast<<<dim3(16, 16), b256, 0, stream>>>(dW1, dW1T, 512, 512, 512, 0);
  transpose_cast<<<dim3(16, 16), b256, 0, stream>>>(dW2, dW2T, 512, 512, 512, 0);
  transpose_cast<<<dim3(8, 16),  b256, 0, stream>>>(eW1, eW1T, 512, 256, 512, 0);
  for (int h = 0; h < 4; ++h)
    transpose_cast<<<dim3(16, 16), b256, 0, stream>>>(Gr + (size_t)h * 512 * 512,
                                                      GTc, 512, 512, 2048, h * 512);
  // ---- denoise MLP ----
  gemm_bt<<<dim3(4, 64), b256, 0, stream>>>(Xb, 512, dW1T, 512, 512, 0, db1,
                                            (const float*)nullptr, 0,
                                            (float*)nullptr, Hb, 512, 1.0f);
  gemm_bt<<<dim3(4, 64), b256, 0, stream>>>(Hb, 512, dW2T, 512, 512, 1, db2,
                                            raw, 512, outD, (short*)nullptr, 512, 1.0f);
  transpose_cast<<<dim3(16, 256), b256, 0, stream>>>(outD, denT, NC, 512, NC, 0);
  // ---- embed + quality ----
  gemm_bt<<<dim3(2, 64), b256, 0, stream>>>(Xb, 512, eW1T, 512, 512, 0, eb1,
                                            (const float*)nullptr, 0,
                                            (float*)nullptr, Hb, 256, 1.0f);
  embed2_kernel<<<dim3(NC / 8), b256, 0, stream>>>(Hb, eW2, eb2, Tr, encb, sqv, Ahb);
  quality_kernel<<<dim3(NC / 4), b256, 0, stream>>>(raw, qW1, qb1, qW2, qb2, Ev);
  // ---- smooth: P = E_j * exp(-dist); outS = outF = (P @ denoised) / rowsum ----
  hipMemsetAsync(lv, 0, NC * 4, stream);
  score_kernel<<<dim3(NC / 1024, NC / 32), b256, 0, stream>>>(
      encb, encb, sqv, Ev, lv, Pbuf, 0);
  gemm_bt<<<dim3(4, 64), b256, 0, stream>>>(Pbuf, NC, denT, NC, NC,
                                            5, (const float*)nullptr,
                                            lv, 0, outS, (short*)outF, 512, 1.0f);
  transpose_cast<<<dim3(16, 256), b256, 0, stream>>>(outS, smoT, NC, 512, NC, 0);
  // ---- interaction heads: U_h = sigmoid(Ah.enc^T) @ smoothed  (bf16, concat) ----
  for (int h = 0; h < 4; ++h){
    score_kernel<<<dim3(NC / 1024, NC / 32), b256, 0, stream>>>(
        encb, Ahb + (size_t)h * NC * 32, sqv, Ev, (float*)nullptr, Pbuf, 1);
    gemm_bt<<<dim3(4, 64), b256, 0, stream>>>(Pbuf, NC, smoT, NC, NC,
                                              6, (const float*)nullptr,
                                              (const float*)nullptr, 0,
                                              (float*)nullptr, Ucat + h * 512, 2048, 1.0f);
  }
  // ---- final += (Ucat @ GTcat^T) / N   (single K=2048 GEMM) ----
  gemm_bt<<<dim3(4, 64), b256, 0, stream>>>(Ucat, 2048, GTc, 2048, 2048,
                                            3, (const float*)nullptr,
                                            (const float*)nullptr, 0,
                                            outF, (short*)nullptr, 512, 1.0f / NC);
}

// Round 3
// 1387.548 us; speedup vs baseline: 1.0544x; 1.0544x over previous
//
#include <hip/hip_runtime.h>
#include <hip/hip_bf16.h>
#include <stdint.h>

#define NC 8192
#define GG 512

typedef __attribute__((ext_vector_type(8))) short bf16x8;   // 8 bf16 = 4 VGPRs (MFMA A/B frag)
typedef __attribute__((ext_vector_type(4))) float fx4;      // MFMA C/D frag

__device__ __forceinline__ float bf2f(short s){
  union { uint32_t u; float f; } c; c.u = ((uint32_t)(uint16_t)s) << 16; return c.f;
}
__device__ __forceinline__ short f2bf(float f){
  union { float f; uint32_t u; } c; c.f = f;
  uint32_t u = c.u;
  uint32_t r = (u + 0x7fffu + ((u >> 16) & 1u)) >> 16;   // RNE
  return (short)(uint16_t)r;
}
__device__ __forceinline__ void g2l16(const void* g, void* l){
  __builtin_amdgcn_global_load_lds((const __attribute__((address_space(1))) void*)g,
                                   (__attribute__((address_space(3))) void*)l, 16, 0, 0);
}

// ---------------- elementwise casts ----------------
__global__ void cast_f32_bf16(const float* __restrict__ in, short* __restrict__ out, int n){
  int i = (blockIdx.x * 256 + threadIdx.x) * 4;
  if (i < n){
    float4 v = *(const float4*)(in + i);
    uint32_t lo = (uint32_t)(uint16_t)f2bf(v.x) | ((uint32_t)(uint16_t)f2bf(v.y) << 16);
    uint32_t hi = (uint32_t)(uint16_t)f2bf(v.z) | ((uint32_t)(uint16_t)f2bf(v.w) << 16);
    *(uint2*)(out + i) = make_uint2(lo, hi);
  }
}

// in f32 [R][C] -> out bf16 at out[c*ostride + roff + r]  (transpose + cast)
__global__ void transpose_cast(const float* __restrict__ in, short* __restrict__ out,
                               int R, int C, int ostride, int roff){
  __shared__ float t[32][33];
  int c0 = blockIdx.x * 32, r0 = blockIdx.y * 32;
  int x = threadIdx.x & 31, y = threadIdx.x >> 5;  // y in 0..7
  #pragma unroll
  for (int it = 0; it < 4; ++it)
    t[y + 8*it][x] = in[(size_t)(r0 + y + 8*it) * C + c0 + x];
  __syncthreads();
  #pragma unroll
  for (int it = 0; it < 4; ++it)
    out[(size_t)(c0 + y + 8*it) * ostride + roff + r0 + x] = f2bf(t[x][y + 8*it]);
}

// ---------------- GEMM: C[M][N] = A[M][K] @ B[N][K]^T ----------------
// BM=64 BN=128 BK=64, 4 waves as 2x2 of [32m x 64n], 16x16x32 bf16 MFMA.
// grid (N/128, M/64) -> 512 blocks for N=512: 2 blocks/CU (R2 lesson: never 1/CU).
// modes: 0 = outb = bf16(tanh(c+bias)); 1 = outf = c+bias+res; 3 = outf += scale*c
// XOR-swizzle (8-elem chunks by row&7) keeps both staging and ds_read_b128 conflict-free.
__global__ __launch_bounds__(256, 2)
void gemm_bt(const short* __restrict__ A, int lda, const short* __restrict__ B, int ldb,
             int K, int mode, const float* __restrict__ bias,
             const float* __restrict__ res, int ldres,
             float* __restrict__ outf, short* __restrict__ outb, int ldo, float scale)
{
  __shared__ __align__(16) short As[64 * 64];
  __shared__ __align__(16) short Bs[128 * 64];
  const int tid = threadIdx.x;
  const int lane = tid & 63, wave = tid >> 6;
  const int wm = wave >> 1, wn = wave & 1;
  const int l16 = lane & 15, q = lane >> 4;
  const size_t i0 = (size_t)blockIdx.y * 64;
  const int n0 = blockIdx.x * 128;
  fx4 acc[2][4] = {};

  for (int k0 = 0; k0 < K; k0 += 64){
    #pragma unroll
    for (int inst = 0; inst < 2; ++inst){              // A tile 64x64 = 8KB
      int ch = inst * 256 + tid;
      int r = ch >> 3, pc = ch & 7;
      int colc = (pc ^ (r & 7)) * 8;
      g2l16(A + (i0 + r) * (size_t)lda + k0 + colc, As + ch * 8);
    }
    #pragma unroll
    for (int inst = 0; inst < 4; ++inst){              // B tile 128x64 = 16KB
      int ch = inst * 256 + tid;
      int r = ch >> 3, pc = ch & 7;
      int colc = (pc ^ (r & 7)) * 8;
      g2l16(B + (size_t)(n0 + r) * (size_t)ldb + k0 + colc, Bs + ch * 8);
    }
    __syncthreads();
    #pragma unroll
    for (int ks = 0; ks < 2; ++ks){
      int k8 = ks * 4 + q;
      bf16x8 af[2], bfr[4];
      #pragma unroll
      for (int mi = 0; mi < 2; ++mi){
        int r = wm * 32 + mi * 16 + l16;
        af[mi] = *(const bf16x8*)(As + r * 64 + ((k8 ^ (r & 7)) << 3));
      }
      #pragma unroll
      for (int ni = 0; ni < 4; ++ni){
        int r = wn * 64 + ni * 16 + l16;
        bfr[ni] = *(const bf16x8*)(Bs + r * 64 + ((k8 ^ (r & 7)) << 3));
      }
      #pragma unroll
      for (int mi = 0; mi < 2; ++mi)
        #pragma unroll
        for (int ni = 0; ni < 4; ++ni)
          acc[mi][ni] = __builtin_amdgcn_mfma_f32_16x16x32_bf16(af[mi], bfr[ni], acc[mi][ni], 0, 0, 0);
    }
    __syncthreads();
  }
  // epilogue: C frag layout col=lane&15 (n), row=q*4+r (m)  [HW-verified R1]
  #pragma unroll
  for (int mi = 0; mi < 2; ++mi){
    #pragma unroll
    for (int ni = 0; ni < 4; ++ni){
      int n = n0 + wn * 64 + ni * 16 + l16;
      float b = bias ? bias[n] : 0.0f;
      #pragma unroll
      for (int r = 0; r < 4; ++r){
        size_t m = i0 + wm * 32 + mi * 16 + q * 4 + r;
        float v = acc[mi][ni][r];
        size_t o = m * (size_t)ldo + n;
        if (mode == 0)      outb[o] = f2bf(tanhf(v + b));
        else if (mode == 1) outf[o] = v + b + res[m * (size_t)ldres + n];
        else                outf[o] += v * scale;   // mode 3
      }
    }
  }
}

// ---------------- fused attention: OUT[i][g] = f(scores(i,:)) @ V ----------------
// mode 0 (smooth): P_ij = E_j*exp(-sqrt(max(sq_i+sq_j-2*enc_i.enc_j,0)));
//                  OUT = (P @ V) / rowsum(P); dual f32 write (out0,out1). V = denoised^T.
// mode 1 (heads):  P_ij = sigmoid(Ah_i . enc_j); OUT(bf16,ld=ldo) = P @ V. V = smoothed^T.
// Block: 64 i-rows x 128 g-cols, j-loop over all 8192 in chunks of 64. P never hits HBM.
// QK tile computed TRANSPOSED (m=j, n=i) so each lane's 4 C-values are j-consecutive ->
// one packed ds_write_b64 into P_lds[i][j]; PV then reads A-frags (i-row, j-contig) as
// swizzled ds_read_b128. Row sums accumulate in-register (block sees all j): no atomics.
__global__ __launch_bounds__(256, 2)
void attn_fused(const short* __restrict__ encA,   // i-side rows [head][NC][32]
                const short* __restrict__ encJ,   // j-side enc [NC][32]
                const short* __restrict__ VT,     // V^T [512][NC] bf16
                const float* __restrict__ sq, const float* __restrict__ E,
                float* __restrict__ out0, float* __restrict__ out1,
                short* __restrict__ outb, int ldo, int mode)
{
  __shared__ __align__(16) short Pl[64 * 64];     // 8 KB
  __shared__ __align__(16) short Vl[128 * 64];    // 16 KB
  __shared__ float lsum[64][2];
  const int tid = threadIdx.x;
  const int lane = tid & 63, wave = tid >> 6;
  const int l16 = lane & 15, q = lane >> 4;
  const int wa = wave >> 1, wb = wave & 1;        // QK: j-half / i-half
  const int wm = wave >> 1, wn = wave & 1;        // PV: i-half / g-half
  const size_t i0 = (size_t)blockIdx.y * 64;
  const int n0 = blockIdx.x * 128;
  const short* Arow = encA + (size_t)blockIdx.z * NC * 32;

  // register-resident B-frags for QK: i-side rows (B[n=l16][k=q*8+j] layout)
  bf16x8 bi[2];
  #pragma unroll
  for (int ni = 0; ni < 2; ++ni)
    bi[ni] = *(const bf16x8*)(Arow + (i0 + wb * 32 + ni * 16 + l16) * 32 + q * 8);
  float sqi[2] = {0.f, 0.f}, lacc[2] = {0.f, 0.f};
  if (mode == 0){
    sqi[0] = sq[i0 + wb * 32 + l16];
    sqi[1] = sq[i0 + wb * 32 + 16 + l16];
  }
  fx4 acc[2][4] = {};

  for (int jc = 0; jc < NC; jc += 64){
    // ---- QK^T (transposed tile: m=j, n=i) + transform, all in registers ----
    uint2 pw[2][2];
    #pragma unroll
    for (int mj = 0; mj < 2; ++mj){
      bf16x8 aj = *(const bf16x8*)(encJ + (size_t)(jc + wa * 32 + mj * 16 + l16) * 32 + q * 8);
      float4 sqj = make_float4(0,0,0,0), Ej = make_float4(0,0,0,0);
      if (mode == 0){
        sqj = *(const float4*)(sq + jc + wa * 32 + mj * 16 + q * 4);
        Ej  = *(const float4*)(E  + jc + wa * 32 + mj * 16 + q * 4);
      }
      #pragma unroll
      for (int ni = 0; ni < 2; ++ni){
        fx4 c = {};
        c = __builtin_amdgcn_mfma_f32_16x16x32_bf16(aj, bi[ni], c, 0, 0, 0);
        short pv[4];
        #pragma unroll
        for (int r = 0; r < 4; ++r){
          float dot = c[r];
          float p;
          if (mode == 0){
            float d2 = fmaxf(sqi[ni] + ((const float*)&sqj)[r] - 2.0f * dot, 0.0f);
            p = ((const float*)&Ej)[r] * __expf(-sqrtf(d2));
            lacc[ni] += p;
          } else {
            p = 1.0f / (1.0f + __expf(-dot));
          }
          pv[r] = f2bf(p);
        }
        pw[mj][ni].x = (uint32_t)(uint16_t)pv[0] | ((uint32_t)(uint16_t)pv[1] << 16);
        pw[mj][ni].y = (uint32_t)(uint16_t)pv[2] | ((uint32_t)(uint16_t)pv[3] << 16);
      }
    }
    __syncthreads();                 // prev chunk's PV reads done before overwrite
    // ---- P tile -> LDS (swizzled [i][j], packed b64) ----
    #pragma unroll
    for (int mj = 0; mj < 2; ++mj)
      #pragma unroll
      for (int ni = 0; ni < 2; ++ni){
        int i = wb * 32 + ni * 16 + l16;
        int jb = wa * 32 + mj * 16 + q * 4;            // 4 consecutive j
        int addr = i * 64 + (((jb >> 3) ^ (i & 7)) << 3) + (jb & 7);
        *(uint2*)(Pl + addr) = pw[mj][ni];
      }
    // ---- stage V chunk [128g][64j] via global_load_lds ----
    #pragma unroll
    for (int inst = 0; inst < 4; ++inst){
      int ch = inst * 256 + tid;
      int r = ch >> 3, pc = ch & 7;
      int colc = (pc ^ (r & 7)) * 8;
      g2l16(VT + (size_t)(n0 + r) * NC + jc + colc, Vl + ch * 8);
    }
    __syncthreads();
    // ---- PV MFMA ----
    #pragma unroll
    for (int ks = 0; ks < 2; ++ks){
      int k8 = ks * 4 + q;
      bf16x8 af[2], bfr[4];
      #pragma unroll
      for (int mi = 0; mi < 2; ++mi){
        int r = wm * 32 + mi * 16 + l16;
        af[mi] = *(const bf16x8*)(Pl + r * 64 + ((k8 ^ (r & 7)) << 3));
      }
      #pragma unroll
      for (int ni = 0; ni < 4; ++ni){
        int r = wn * 64 + ni * 16 + l16;
        bfr[ni] = *(const bf16x8*)(Vl + r * 64 + ((k8 ^ (r & 7)) << 3));
      }
      #pragma unroll
      for (int mi = 0; mi < 2; ++mi)
        #pragma unroll
        for (int ni = 0; ni < 4; ++ni)
          acc[mi][ni] = __builtin_amdgcn_mfma_f32_16x16x32_bf16(af[mi], bfr[ni], acc[mi][ni], 0, 0, 0);
    }
  }

  if (mode == 0){
    // finalize row sums: reduce over q (j-quads) then across the two j-half waves
    #pragma unroll
    for (int ni = 0; ni < 2; ++ni){
      float v = lacc[ni];
      v += __shfl_xor(v, 16);
      v += __shfl_xor(v, 32);
      if (lane < 16) lsum[wb * 32 + ni * 16 + lane][wa] = v;
    }
  }
  __syncthreads();

  #pragma unroll
  for (int mi = 0; mi < 2; ++mi){
    float inv[4];
    if (mode == 0){
      #pragma unroll
      for (int r = 0; r < 4; ++r){
        int il = wm * 32 + mi * 16 + q * 4 + r;
        inv[r] = 1.0f / (lsum[il][0] + lsum[il][1]);
      }
    }
    #pragma unroll
    for (int ni = 0; ni < 4; ++ni){
      int g = n0 + wn * 64 + ni * 16 + l16;
      #pragma unroll
      for (int r = 0; r < 4; ++r){
        size_t m = i0 + wm * 32 + mi * 16 + q * 4 + r;
        if (mode == 0){
          float v = acc[mi][ni][r] * inv[r];
          size_t o = m * (size_t)GG + g;
          out0[o] = v; out1[o] = v;
        } else {
          outb[m * (size_t)ldo + (size_t)blockIdx.z * GG + g] = f2bf(acc[mi][ni][r]);
        }
      }
    }
  }
}

// ---------------- small MLP tails ----------------
__global__ void embed2_kernel(const short* __restrict__ H2, const float* __restrict__ eW2,
                              const float* __restrict__ eb2, const float* __restrict__ T4,
                              short* __restrict__ encb, float* __restrict__ sq,
                              short* __restrict__ Ah)
{
  __shared__ float encS[8][32];
  int d = threadIdx.x & 31, cl = threadIdx.x >> 5;
  size_t c = (size_t)blockIdx.x * 8 + cl;
  float s = eb2[d];
  const short* hrow = H2 + c * 256;
  for (int k = 0; k < 256; ++k) s += bf2f(hrow[k]) * eW2[k * 32 + d];
  short eb = f2bf(s);
  encb[c * 32 + d] = eb;
  encS[cl][d] = bf2f(eb);
  __syncthreads();
  if (d == 0){
    float t = 0;
    for (int k = 0; k < 32; ++k) t += encS[cl][k] * encS[cl][k];
    sq[c] = t;
  }
  #pragma unroll
  for (int h = 0; h < 4; ++h){
    float a = 0;
    const float* T = T4 + h * 1024;
    for (int k = 0; k < 32; ++k) a += encS[cl][k] * T[k * 32 + d];
    Ah[(size_t)h * NC * 32 + c * 32 + d] = f2bf(a);
  }
}

__global__ void quality_kernel(const float* __restrict__ X, const float* __restrict__ qW1,
                               const float* __restrict__ qb1, const float* __restrict__ qW2,
                               const float* __restrict__ qb2, float* __restrict__ E)
{
  int j = threadIdx.x & 63, cl = threadIdx.x >> 6;
  size_t c = (size_t)blockIdx.x * 4 + cl;
  float s = qb1[j];
  const float* xr = X + c * 512;
  for (int k = 0; k < 512; ++k) s += xr[k] * qW1[k * 64 + j];
  float t = tanhf(s) * qW2[j];
  #pragma unroll
  for (int o = 32; o >= 1; o >>= 1) t += __shfl_xor(t, o);
  if (j == 0) E[c] = __expf(t + qb2[0]);
}

// ---------------- host ----------------
extern "C" void kernel_launch(void* const* d_in, const int* in_sizes, int n_in,
                              void* d_out, int out_size, void* d_ws, size_t ws_size,
                              hipStream_t stream)
{
  const float* raw = (const float*)d_in[0];
  const float* dW1 = (const float*)d_in[1];
  const float* db1 = (const float*)d_in[2];
  const float* dW2 = (const float*)d_in[3];
  const float* db2 = (const float*)d_in[4];
  const float* eW1 = (const float*)d_in[5];
  const float* eb1 = (const float*)d_in[6];
  const float* eW2 = (const float*)d_in[7];
  const float* eb2 = (const float*)d_in[8];
  const float* qW1 = (const float*)d_in[9];
  const float* qb1 = (const float*)d_in[10];
  const float* qW2 = (const float*)d_in[11];
  const float* qb2 = (const float*)d_in[12];
  const float* Tr  = (const float*)d_in[13];
  const float* Gr  = (const float*)d_in[14];

  float* outD = (float*)d_out;                    // denoised [8192][512]
  float* outS = outD + (size_t)NC * GG;           // smoothed
  float* outF = outS + (size_t)NC * GG;           // final

  char* ws = (char*)d_ws;
  size_t off = 0;
  auto take = [&](size_t bytes) -> char* {
    char* p = ws + off; off += (bytes + 255) & ~(size_t)255; return p;
  };
  short* Xb   = (short*)take((size_t)NC * GG * 2);        // raw bf16
  short* dW1T = (short*)take((size_t)512 * 512 * 2);
  short* dW2T = (short*)take((size_t)512 * 512 * 2);
  short* eW1T = (short*)take((size_t)256 * 512 * 2);
  short* GTc  = (short*)take((size_t)512 * 2048 * 2);     // gene_responses^T concat
  short* Hb   = (short*)take((size_t)NC * 512 * 2);       // hidden bf16
  short* denT = (short*)take((size_t)GG * NC * 2);        // denoised^T
  short* smoT = (short*)take((size_t)GG * NC * 2);        // smoothed^T
  short* encb = (short*)take((size_t)NC * 32 * 2);
  short* Ahb  = (short*)take((size_t)4 * NC * 32 * 2);
  float* sqv  = (float*)take((size_t)NC * 4);
  float* Ev   = (float*)take((size_t)NC * 4);
  short* Ucat = (short*)take((size_t)NC * 2048 * 2);      // head outputs concat

  dim3 b256(256);
  // ---- casts / transposed weights ----
  cast_f32_bf16<<<dim3((NC * GG) / 1024), b256, 0, stream>>>(raw, Xb, NC * GG);
  transpose_cast<<<dim3(16, 16), b256, 0, stream>>>(dW1, dW1T, 512, 512, 512, 0);
  transpose_cast<<<dim3(16, 16), b256, 0, stream>>>(dW2, dW2T, 512, 512, 512, 0);
  transpose_cast<<<dim3(8, 16),  b256, 0, stream>>>(eW1, eW1T, 512, 256, 512, 0);
  for (int h = 0; h < 4; ++h)
    transpose_cast<<<dim3(16, 16), b256, 0, stream>>>(Gr + (size_t)h * 512 * 512,
                                                      GTc, 512, 512, 2048, h * 512);
  // ---- denoise MLP ----
  gemm_bt<<<dim3(4, 128), b256, 0, stream>>>(Xb, 512, dW1T, 512, 512, 0, db1,
                                             (const float*)nullptr, 0,
                                             (float*)nullptr, Hb, 512, 1.0f);
  gemm_bt<<<dim3(4, 128), b256, 0, stream>>>(Hb, 512, dW2T, 512, 512, 1, db2,
                                             raw, 512, outD, (short*)nullptr, 512, 1.0f);
  transpose_cast<<<dim3(16, 256), b256, 0, stream>>>(outD, denT, NC, 512, NC, 0);
  // ---- embed + quality ----
  gemm_bt<<<dim3(2, 128), b256, 0, stream>>>(Xb, 512, eW1T, 512, 512, 0, eb1,
                                             (const float*)nullptr, 0,
                                             (float*)nullptr, Hb, 256, 1.0f);
  embed2_kernel<<<dim3(NC / 8), b256, 0, stream>>>(Hb, eW2, eb2, Tr, encb, sqv, Ahb);
  quality_kernel<<<dim3(NC / 4), b256, 0, stream>>>(raw, qW1, qb1, qW2, qb2, Ev);
  // ---- fused smooth: outS = outF = softmax-weighted avg of denoised ----
  attn_fused<<<dim3(4, 128, 1), b256, 0, stream>>>(encb, encb, denT, sqv, Ev,
                                                   outS, outF, (short*)nullptr, 0, 0);
  transpose_cast<<<dim3(16, 256), b256, 0, stream>>>(outS, smoT, NC, 512, NC, 0);
  // ---- fused heads: Ucat[:, h*512:] = sigmoid(Ah_h enc^T) @ smoothed ----
  attn_fused<<<dim3(4, 128, 4), b256, 0, stream>>>(Ahb, encb, smoT, sqv, Ev,
                                                   (float*)nullptr, (float*)nullptr,
                                                   Ucat, 2048, 1);
  // ---- final += (Ucat @ GTcat^T) / N   (single K=2048 GEMM) ----
  gemm_bt<<<dim3(4, 128), b256, 0, stream>>>(Ucat, 2048, GTc, 2048, 2048,
                                             3, (const float*)nullptr,
                                             (const float*)nullptr, 0,
                                             outF, (short*)nullptr, 512, 1.0f / NC);
}

// Round 4
// 1021.777 us; speedup vs baseline: 1.4319x; 1.3580x over previous
//
#include <hip/hip_runtime.h>
#include <hip/hip_bf16.h>
#include <stdint.h>

#define NC 8192
#define GG 512

typedef __attribute__((ext_vector_type(8))) short bf16x8;   // 8 bf16 = 4 VGPRs (MFMA A/B frag)
typedef __attribute__((ext_vector_type(4))) float fx4;      // MFMA C/D frag
typedef __attribute__((ext_vector_type(4))) unsigned int uint4v;

__device__ __forceinline__ float bf2f(short s){
  union { uint32_t u; float f; } c; c.u = ((uint32_t)(uint16_t)s) << 16; return c.f;
}
__device__ __forceinline__ short f2bf(float f){
  union { float f; uint32_t u; } c; c.f = f;
  uint32_t u = c.u;
  uint32_t r = (u + 0x7fffu + ((u >> 16) & 1u)) >> 16;   // RNE
  return (short)(uint16_t)r;
}
__device__ __forceinline__ uint32_t au(float f){
  union { float f; uint32_t u; } c; c.f = f; return c.u;
}
#if __has_builtin(__builtin_amdgcn_rcpf)
__device__ __forceinline__ float fast_rcp(float x){ return __builtin_amdgcn_rcpf(x); }
#else
__device__ __forceinline__ float fast_rcp(float x){ return 1.0f / x; }
#endif
#if __has_builtin(__builtin_amdgcn_sqrtf)
__device__ __forceinline__ float fast_sqrt(float x){ return __builtin_amdgcn_sqrtf(x); }
#else
__device__ __forceinline__ float fast_sqrt(float x){ return sqrtf(x); }
#endif
// pack two floats -> bf16 pair (round-half-up via +0x8000, then byte-perm hi16s)
__device__ __forceinline__ uint32_t pack_bf(float lo, float hi){
  return __builtin_amdgcn_perm(au(hi) + 0x8000u, au(lo) + 0x8000u, 0x07060302u);
}
__device__ __forceinline__ void g2l16(const void* g, void* l){
  __builtin_amdgcn_global_load_lds((const __attribute__((address_space(1))) void*)g,
                                   (__attribute__((address_space(3))) void*)l, 16, 0, 0);
}

// ---------------- elementwise casts ----------------
__global__ void cast_f32_bf16(const float* __restrict__ in, short* __restrict__ out, int n){
  int i = (blockIdx.x * 256 + threadIdx.x) * 4;
  if (i < n){
    float4 v = *(const float4*)(in + i);
    uint32_t lo = (uint32_t)(uint16_t)f2bf(v.x) | ((uint32_t)(uint16_t)f2bf(v.y) << 16);
    uint32_t hi = (uint32_t)(uint16_t)f2bf(v.z) | ((uint32_t)(uint16_t)f2bf(v.w) << 16);
    *(uint2*)(out + i) = make_uint2(lo, hi);
  }
}

// in f32 [R][C] -> out bf16 at out[c*ostride + roff + r']  (transpose + cast)
// permute!=0: r' permuted within each 32-group to the MFMA k-order
// (j = jt*16+q*4+r  ->  pos = q*8+jt*4+r) so PV B-frags can come straight
// from QK C-frag registers (k-order must match between A and B operands).
__global__ void transpose_cast(const float* __restrict__ in, short* __restrict__ out,
                               int R, int C, int ostride, int roff, int permute){
  __shared__ float t[32][33];
  int c0 = blockIdx.x * 32, r0 = blockIdx.y * 32;
  int x = threadIdx.x & 31, y = threadIdx.x >> 5;  // y in 0..7
  #pragma unroll
  for (int it = 0; it < 4; ++it)
    t[y + 8*it][x] = in[(size_t)(r0 + y + 8*it) * C + c0 + x];
  __syncthreads();
  int xp = permute ? (((x >> 2) & 3) * 8 + ((x >> 4) & 1) * 4 + (x & 3)) : x;
  #pragma unroll
  for (int it = 0; it < 4; ++it)
    out[(size_t)(c0 + y + 8*it) * ostride + roff + r0 + xp] = f2bf(t[x][y + 8*it]);
}

// ---------------- GEMM: C[M][N] = A[M][K] @ B[N][K]^T ----------------
// BM=64 BN=128 BK=64, 4 waves as 2x2 of [32m x 64n], 16x16x32 bf16 MFMA.
// modes: 0 = outb = bf16(tanh(c+bias)); 1 = outf = c+bias+res; 3 = outf += scale*c
__global__ __launch_bounds__(256, 2)
void gemm_bt(const short* __restrict__ A, int lda, const short* __restrict__ B, int ldb,
             int K, int mode, const float* __restrict__ bias,
             const float* __restrict__ res, int ldres,
             float* __restrict__ outf, short* __restrict__ outb, int ldo, float scale)
{
  __shared__ __align__(16) short As[64 * 64];
  __shared__ __align__(16) short Bs[128 * 64];
  const int tid = threadIdx.x;
  const int lane = tid & 63, wave = tid >> 6;
  const int wm = wave >> 1, wn = wave & 1;
  const int l16 = lane & 15, q = lane >> 4;
  const size_t i0 = (size_t)blockIdx.y * 64;
  const int n0 = blockIdx.x * 128;
  fx4 acc[2][4] = {};

  for (int k0 = 0; k0 < K; k0 += 64){
    #pragma unroll
    for (int inst = 0; inst < 2; ++inst){              // A tile 64x64 = 8KB
      int ch = inst * 256 + tid;
      int r = ch >> 3, pc = ch & 7;
      int colc = (pc ^ (r & 7)) * 8;
      g2l16(A + (i0 + r) * (size_t)lda + k0 + colc, As + ch * 8);
    }
    #pragma unroll
    for (int inst = 0; inst < 4; ++inst){              // B tile 128x64 = 16KB
      int ch = inst * 256 + tid;
      int r = ch >> 3, pc = ch & 7;
      int colc = (pc ^ (r & 7)) * 8;
      g2l16(B + (size_t)(n0 + r) * (size_t)ldb + k0 + colc, Bs + ch * 8);
    }
    __syncthreads();
    #pragma unroll
    for (int ks = 0; ks < 2; ++ks){
      int k8 = ks * 4 + q;
      bf16x8 af[2], bfr[4];
      #pragma unroll
      for (int mi = 0; mi < 2; ++mi){
        int r = wm * 32 + mi * 16 + l16;
        af[mi] = *(const bf16x8*)(As + r * 64 + ((k8 ^ (r & 7)) << 3));
      }
      #pragma unroll
      for (int ni = 0; ni < 4; ++ni){
        int r = wn * 64 + ni * 16 + l16;
        bfr[ni] = *(const bf16x8*)(Bs + r * 64 + ((k8 ^ (r & 7)) << 3));
      }
      #pragma unroll
      for (int mi = 0; mi < 2; ++mi)
        #pragma unroll
        for (int ni = 0; ni < 4; ++ni)
          acc[mi][ni] = __builtin_amdgcn_mfma_f32_16x16x32_bf16(af[mi], bfr[ni], acc[mi][ni], 0, 0, 0);
    }
    __syncthreads();
  }
  // epilogue: C frag layout col=lane&15 (n), row=q*4+r (m)  [HW-verified R1]
  #pragma unroll
  for (int mi = 0; mi < 2; ++mi){
    #pragma unroll
    for (int ni = 0; ni < 4; ++ni){
      int n = n0 + wn * 64 + ni * 16 + l16;
      float b = bias ? bias[n] : 0.0f;
      #pragma unroll
      for (int r = 0; r < 4; ++r){
        size_t m = i0 + wm * 32 + mi * 16 + q * 4 + r;
        float v = acc[mi][ni][r];
        size_t o = m * (size_t)ldo + n;
        if (mode == 0)      outb[o] = f2bf(tanhf(v + b));
        else if (mode == 1) outf[o] = v + b + res[m * (size_t)ldres + n];
        else                outf[o] += v * scale;   // mode 3
      }
    }
  }
}

// ---------------- fused attention, register-resident P ----------------
// MODE 0 (smooth): P_ij = E_j*exp(-sqrt(max(sq_i+sq_j-2*enc_i.enc_j,0)));
//                  OUT[i][g] = (P @ V)/rowsum(P), dual f32 write. V = denoisedT (permuted).
// MODE 1 (heads):  P_ij = sigmoid(Ah_i . enc_j); OUT bf16 at [i][z*GG+g]. V = smoothedT (perm).
// Block IT i-rows x GT g-cols; 4 waves as 2x2 (i-half x g-half). j-loop chunks of 64.
// QK computed TRANSPOSED (m=j, n=i): C-frag lane l16=i holds j={jt*16+q*4+r} -> packed
// directly into the PV B-operand (k-order matched by VTp's baked-in j-permutation).
// P touches NO memory. Only V staged to LDS (single buffer; QK compute fills DMA window).
template<int IT, int GT, int MODE>
__global__ __launch_bounds__(256, 2)
void attn_reg(const short* __restrict__ encA,   // i-side rows [z][NC][32]
              const short* __restrict__ encJ,   // j-side enc [NC][32]
              const short* __restrict__ VTp,    // V^T [GG][NC] bf16, j-permuted per 32
              const float* __restrict__ sq, const float* __restrict__ E,
              float* __restrict__ out0, float* __restrict__ out1,
              short* __restrict__ outb, int ldo)
{
  constexpr int NI = IT / 32;                   // i-tiles per wave (i-half split)
  constexpr int NG = GT / 32;                   // g-tiles per wave (g-half split)
  __shared__ __align__(16) short Vl[GT * 64];
  const int tid = threadIdx.x, lane = tid & 63, wave = tid >> 6;
  const int l16 = lane & 15, q = lane >> 4;
  const int wi = wave >> 1, wg = wave & 1;
  const int i0 = blockIdx.y * IT + wi * (IT / 2);
  const int g0 = blockIdx.x * GT;
  const int gw = wg * (GT / 2);
  const short* Ai = encA + (size_t)blockIdx.z * NC * 32;

  bf16x8 bi[NI];
  float sqi[NI], lacc[NI];
  #pragma unroll
  for (int t = 0; t < NI; ++t){
    bi[t] = *(const bf16x8*)(Ai + (size_t)(i0 + t * 16 + l16) * 32 + q * 8);
    if (MODE == 0){ sqi[t] = sq[i0 + t * 16 + l16]; lacc[t] = 0.f; }
  }
  fx4 acc[NI][NG] = {};

  for (int jc = 0; jc < NC; jc += 64){
    __syncthreads();                            // all waves done reading Vl (prev chunk)
    #pragma unroll
    for (int inst = 0; inst < GT / 32; ++inst){ // stage V chunk GTx64 via DMA
      int ch = inst * 256 + tid;
      int r = ch >> 3, pc = ch & 7;
      int colc = (pc ^ (r & 7)) * 8;
      g2l16(VTp + (size_t)(g0 + r) * NC + jc + colc, Vl + ch * 8);
    }
    // ---- QK + transform -> B-operand frags in registers (fills DMA window) ----
    uint4v bP[2][NI];
    #pragma unroll
    for (int ks = 0; ks < 2; ++ks){
      int jb = jc + ks * 32;
      uint32_t dw[NI][4];
      #pragma unroll
      for (int jt = 0; jt < 2; ++jt){
        bf16x8 aj = *(const bf16x8*)(encJ + (size_t)(jb + jt * 16 + l16) * 32 + q * 8);
        float4 sqj = make_float4(0,0,0,0), Ej = make_float4(0,0,0,0);
        if (MODE == 0){
          sqj = *(const float4*)(sq + jb + jt * 16 + q * 4);
          Ej  = *(const float4*)(E  + jb + jt * 16 + q * 4);
        }
        #pragma unroll
        for (int t = 0; t < NI; ++t){
          fx4 c = {};
          c = __builtin_amdgcn_mfma_f32_16x16x32_bf16(aj, bi[t], c, 0, 0, 0);
          float pv[4];
          #pragma unroll
          for (int r = 0; r < 4; ++r){
            float dot = c[r];
            if (MODE == 0){
              float d2 = fmaxf(sqi[t] + ((const float*)&sqj)[r] - 2.0f * dot, 0.0f);
              float p = ((const float*)&Ej)[r] * __expf(-fast_sqrt(d2));
              lacc[t] += p;
              pv[r] = p;
            } else {
              pv[r] = fast_rcp(1.0f + __expf(-dot));
            }
          }
          dw[t][jt * 2 + 0] = pack_bf(pv[0], pv[1]);
          dw[t][jt * 2 + 1] = pack_bf(pv[2], pv[3]);
        }
      }
      #pragma unroll
      for (int t = 0; t < NI; ++t){
        uint4v u = { dw[t][0], dw[t][1], dw[t][2], dw[t][3] };
        bP[ks][t] = u;
      }
    }
    __syncthreads();                            // V staged (compiler drains vmcnt here)
    // ---- PV MFMA: D[m=g][n=i] += V * P ----
    #pragma unroll
    for (int ks = 0; ks < 2; ++ks){
      int k8 = ks * 4 + q;
      #pragma unroll
      for (int gt = 0; gt < NG; ++gt){
        int rr = gw + gt * 16 + l16;
        bf16x8 av = *(const bf16x8*)(Vl + rr * 64 + ((k8 ^ (rr & 7)) << 3));
        #pragma unroll
        for (int t = 0; t < NI; ++t)
          acc[t][gt] = __builtin_amdgcn_mfma_f32_16x16x32_bf16(
              av, *(const bf16x8*)&bP[ks][t], acc[t][gt], 0, 0, 0);
      }
    }
  }

  // ---- epilogue: D frag col = i (l16), row = g (q*4+r) ----
  float inv[NI];
  if (MODE == 0){
    #pragma unroll
    for (int t = 0; t < NI; ++t){               // reduce lacc over the 4 q-lanes per l16
      float v = lacc[t];
      v += __shfl_xor(v, 16);
      v += __shfl_xor(v, 32);
      inv[t] = fast_rcp(v);
    }
  }
  #pragma unroll
  for (int t = 0; t < NI; ++t){
    int i = i0 + t * 16 + l16;
    #pragma unroll
    for (int gt = 0; gt < NG; ++gt){
      int g = g0 + gw + gt * 16 + q * 4;
      if (MODE == 0){
        float4 v;
        v.x = acc[t][gt][0] * inv[t]; v.y = acc[t][gt][1] * inv[t];
        v.z = acc[t][gt][2] * inv[t]; v.w = acc[t][gt][3] * inv[t];
        size_t o = (size_t)i * GG + g;
        *(float4*)(out0 + o) = v;
        *(float4*)(out1 + o) = v;
      } else {
        uint2 u;
        u.x = (uint32_t)(uint16_t)f2bf(acc[t][gt][0]) | ((uint32_t)(uint16_t)f2bf(acc[t][gt][1]) << 16);
        u.y = (uint32_t)(uint16_t)f2bf(acc[t][gt][2]) | ((uint32_t)(uint16_t)f2bf(acc[t][gt][3]) << 16);
        *(uint2*)(outb + (size_t)i * ldo + (size_t)blockIdx.z * GG + g) = u;
      }
    }
  }
}

// ---------------- small MLP tails ----------------
__global__ void embed2_kernel(const short* __restrict__ H2, const float* __restrict__ eW2,
                              const float* __restrict__ eb2, const float* __restrict__ T4,
                              short* __restrict__ encb, float* __restrict__ sq,
                              short* __restrict__ Ah)
{
  __shared__ float encS[8][32];
  int d = threadIdx.x & 31, cl = threadIdx.x >> 5;
  size_t c = (size_t)blockIdx.x * 8 + cl;
  float s = eb2[d];
  const short* hrow = H2 + c * 256;
  for (int k = 0; k < 256; ++k) s += bf2f(hrow[k]) * eW2[k * 32 + d];
  short eb = f2bf(s);
  encb[c * 32 + d] = eb;
  encS[cl][d] = bf2f(eb);
  __syncthreads();
  if (d == 0){
    float t = 0;
    for (int k = 0; k < 32; ++k) t += encS[cl][k] * encS[cl][k];
    sq[c] = t;
  }
  #pragma unroll
  for (int h = 0; h < 4; ++h){
    float a = 0;
    const float* T = T4 + h * 1024;
    for (int k = 0; k < 32; ++k) a += encS[cl][k] * T[k * 32 + d];
    Ah[(size_t)h * NC * 32 + c * 32 + d] = f2bf(a);
  }
}

__global__ void quality_kernel(const float* __restrict__ X, const float* __restrict__ qW1,
                               const float* __restrict__ qb1, const float* __restrict__ qW2,
                               const float* __restrict__ qb2, float* __restrict__ E)
{
  int j = threadIdx.x & 63, cl = threadIdx.x >> 6;
  size_t c = (size_t)blockIdx.x * 4 + cl;
  float s = qb1[j];
  const float* xr = X + c * 512;
  for (int k = 0; k < 512; ++k) s += xr[k] * qW1[k * 64 + j];
  float t = tanhf(s) * qW2[j];
  #pragma unroll
  for (int o = 32; o >= 1; o >>= 1) t += __shfl_xor(t, o);
  if (j == 0) E[c] = __expf(t + qb2[0]);
}

// ---------------- host ----------------
extern "C" void kernel_launch(void* const* d_in, const int* in_sizes, int n_in,
                              void* d_out, int out_size, void* d_ws, size_t ws_size,
                              hipStream_t stream)
{
  const float* raw = (const float*)d_in[0];
  const float* dW1 = (const float*)d_in[1];
  const float* db1 = (const float*)d_in[2];
  const float* dW2 = (const float*)d_in[3];
  const float* db2 = (const float*)d_in[4];
  const float* eW1 = (const float*)d_in[5];
  const float* eb1 = (const float*)d_in[6];
  const float* eW2 = (const float*)d_in[7];
  const float* eb2 = (const float*)d_in[8];
  const float* qW1 = (const float*)d_in[9];
  const float* qb1 = (const float*)d_in[10];
  const float* qW2 = (const float*)d_in[11];
  const float* qb2 = (const float*)d_in[12];
  const float* Tr  = (const float*)d_in[13];
  const float* Gr  = (const float*)d_in[14];

  float* outD = (float*)d_out;                    // denoised [8192][512]
  float* outS = outD + (size_t)NC * GG;           // smoothed
  float* outF = outS + (size_t)NC * GG;           // final

  char* ws = (char*)d_ws;
  size_t off = 0;
  auto take = [&](size_t bytes) -> char* {
    char* p = ws + off; off += (bytes + 255) & ~(size_t)255; return p;
  };
  short* Xb   = (short*)take((size_t)NC * GG * 2);        // raw bf16
  short* dW1T = (short*)take((size_t)512 * 512 * 2);
  short* dW2T = (short*)take((size_t)512 * 512 * 2);
  short* eW1T = (short*)take((size_t)256 * 512 * 2);
  short* GTc  = (short*)take((size_t)512 * 2048 * 2);     // gene_responses^T concat
  short* Hb   = (short*)take((size_t)NC * 512 * 2);       // hidden bf16
  short* denTp= (short*)take((size_t)GG * NC * 2);        // denoised^T, k-permuted
  short* smoTp= (short*)take((size_t)GG * NC * 2);        // smoothed^T, k-permuted
  short* encb = (short*)take((size_t)NC * 32 * 2);
  short* Ahb  = (short*)take((size_t)4 * NC * 32 * 2);
  float* sqv  = (float*)take((size_t)NC * 4);
  float* Ev   = (float*)take((size_t)NC * 4);
  short* Ucat = (short*)take((size_t)NC * 2048 * 2);      // head outputs concat

  dim3 b256(256);
  // ---- casts / transposed weights ----
  cast_f32_bf16<<<dim3((NC * GG) / 1024), b256, 0, stream>>>(raw, Xb, NC * GG);
  transpose_cast<<<dim3(16, 16), b256, 0, stream>>>(dW1, dW1T, 512, 512, 512, 0, 0);
  transpose_cast<<<dim3(16, 16), b256, 0, stream>>>(dW2, dW2T, 512, 512, 512, 0, 0);
  transpose_cast<<<dim3(8, 16),  b256, 0, stream>>>(eW1, eW1T, 512, 256, 512, 0, 0);
  for (int h = 0; h < 4; ++h)
    transpose_cast<<<dim3(16, 16), b256, 0, stream>>>(Gr + (size_t)h * 512 * 512,
                                                      GTc, 512, 512, 2048, h * 512, 0);
  // ---- denoise MLP ----
  gemm_bt<<<dim3(4, 128), b256, 0, stream>>>(Xb, 512, dW1T, 512, 512, 0, db1,
                                             (const float*)nullptr, 0,
                                             (float*)nullptr, Hb, 512, 1.0f);
  gemm_bt<<<dim3(4, 128), b256, 0, stream>>>(Hb, 512, dW2T, 512, 512, 1, db2,
                                             raw, 512, outD, (short*)nullptr, 512, 1.0f);
  transpose_cast<<<dim3(16, 256), b256, 0, stream>>>(outD, denTp, NC, 512, NC, 0, 1);
  // ---- embed + quality ----
  gemm_bt<<<dim3(2, 128), b256, 0, stream>>>(Xb, 512, eW1T, 512, 512, 0, eb1,
                                             (const float*)nullptr, 0,
                                             (float*)nullptr, Hb, 256, 1.0f);
  embed2_kernel<<<dim3(NC / 8), b256, 0, stream>>>(Hb, eW2, eb2, Tr, encb, sqv, Ahb);
  quality_kernel<<<dim3(NC / 4), b256, 0, stream>>>(raw, qW1, qb1, qW2, qb2, Ev);
  // ---- fused smooth: outS = outF = softmax-weighted avg of denoised ----
  attn_reg<64, 128, 0><<<dim3(GG / 128, NC / 64, 1), b256, 0, stream>>>(
      encb, encb, denTp, sqv, Ev, outS, outF, (short*)nullptr, 0);
  transpose_cast<<<dim3(16, 256), b256, 0, stream>>>(outS, smoTp, NC, 512, NC, 0, 1);
  // ---- fused heads: Ucat[:, h*512:] = sigmoid(Ah_h enc^T) @ smoothed ----
  attn_reg<128, 256, 1><<<dim3(GG / 256, NC / 128, 4), b256, 0, stream>>>(
      Ahb, encb, smoTp, sqv, Ev, (float*)nullptr, (float*)nullptr, Ucat, 2048);
  // ---- final += (Ucat @ GTcat^T) / N   (single K=2048 GEMM) ----
  gemm_bt<<<dim3(4, 128), b256, 0, stream>>>(Ucat, 2048, GTc, 2048, 2048,
                                             3, (const float*)nullptr,
                                             (const float*)nullptr, 0,
                                             outF, (short*)nullptr, 512, 1.0f / NC);
}

// Round 5
// 886.301 us; speedup vs baseline: 1.6508x; 1.1529x over previous
//
#include <hip/hip_runtime.h>
#include <hip/hip_bf16.h>
#include <stdint.h>

#define NC 8192
#define GG 512

typedef __attribute__((ext_vector_type(8))) short bf16x8;   // 8 bf16 = 4 VGPRs (MFMA A/B frag)
typedef __attribute__((ext_vector_type(4))) float fx4;      // MFMA C/D frag
typedef __attribute__((ext_vector_type(4))) unsigned int uint4v;

__device__ __forceinline__ float bf2f(short s){
  union { uint32_t u; float f; } c; c.u = ((uint32_t)(uint16_t)s) << 16; return c.f;
}
__device__ __forceinline__ short f2bf(float f){
  union { float f; uint32_t u; } c; c.f = f;
  uint32_t u = c.u;
  uint32_t r = (u + 0x7fffu + ((u >> 16) & 1u)) >> 16;   // RNE
  return (short)(uint16_t)r;
}
__device__ __forceinline__ uint32_t au(float f){
  union { float f; uint32_t u; } c; c.f = f; return c.u;
}
#if __has_builtin(__builtin_amdgcn_rcpf)
__device__ __forceinline__ float fast_rcp(float x){ return __builtin_amdgcn_rcpf(x); }
#else
__device__ __forceinline__ float fast_rcp(float x){ return 1.0f / x; }
#endif
#if __has_builtin(__builtin_amdgcn_sqrtf)
__device__ __forceinline__ float fast_sqrt(float x){ return __builtin_amdgcn_sqrtf(x); }
#else
__device__ __forceinline__ float fast_sqrt(float x){ return sqrtf(x); }
#endif
__device__ __forceinline__ float tanh_fast(float x){      // |err| ~1e-7 rel of rcp: fine at bf16
  float e = __expf(2.0f * x);
  return 1.0f - 2.0f * fast_rcp(e + 1.0f);
}
// pack two floats -> bf16 pair (round-half-up via +0x8000, then byte-perm hi16s)
__device__ __forceinline__ uint32_t pack_bf(float lo, float hi){
  return __builtin_amdgcn_perm(au(hi) + 0x8000u, au(lo) + 0x8000u, 0x07060302u);
}
__device__ __forceinline__ void g2l16(const void* g, void* l){
  __builtin_amdgcn_global_load_lds((const __attribute__((address_space(1))) void*)g,
                                   (__attribute__((address_space(3))) void*)l, 16, 0, 0);
}

// ---------------- elementwise casts ----------------
__global__ void cast_f32_bf16(const float* __restrict__ in, short* __restrict__ out, int n){
  int i = (blockIdx.x * 256 + threadIdx.x) * 4;
  if (i < n){
    float4 v = *(const float4*)(in + i);
    uint32_t lo = (uint32_t)(uint16_t)f2bf(v.x) | ((uint32_t)(uint16_t)f2bf(v.y) << 16);
    uint32_t hi = (uint32_t)(uint16_t)f2bf(v.z) | ((uint32_t)(uint16_t)f2bf(v.w) << 16);
    *(uint2*)(out + i) = make_uint2(lo, hi);
  }
}

// in f32 [R][C] -> out bf16 at out[c*ostride + roff + r']  (transpose + cast)
// permute!=0: r' permuted within each 32-group to the MFMA k-order
// (j = jt*16+q*4+r -> pos = q*8+jt*4+r) so PV B-frags come straight from QK C-frags.
__global__ void transpose_cast(const float* __restrict__ in, short* __restrict__ out,
                               int R, int C, int ostride, int roff, int permute){
  __shared__ float t[32][33];
  int c0 = blockIdx.x * 32, r0 = blockIdx.y * 32;
  int x = threadIdx.x & 31, y = threadIdx.x >> 5;  // y in 0..7
  #pragma unroll
  for (int it = 0; it < 4; ++it)
    t[y + 8*it][x] = in[(size_t)(r0 + y + 8*it) * C + c0 + x];
  __syncthreads();
  int xp = permute ? (((x >> 2) & 3) * 8 + ((x >> 4) & 1) * 4 + (x & 3)) : x;
  #pragma unroll
  for (int it = 0; it < 4; ++it)
    out[(size_t)(c0 + y + 8*it) * ostride + roff + r0 + xp] = f2bf(t[x][y + 8*it]);
}

__global__ void fill_bias(const float* __restrict__ db1, const float* __restrict__ eb1,
                          const float* __restrict__ qb1, float* __restrict__ b){
  int i = blockIdx.x * 256 + threadIdx.x;
  if (i >= 896) return;
  float v = 0.0f;
  if (i < 512) v = db1[i];
  else if (i < 768) v = eb1[i - 512];
  else if (i < 832) v = qb1[i - 768];
  b[i] = v;
}

// ---------------- GEMM: C[M][N] = A[M][K] @ B[N][K]^T ----------------
// BM=64 BN=128 BK=64, 4 waves as 2x2 of [32m x 64n], 16x16x32 bf16 MFMA.
// modes: 0 = outb = bf16(tanh(c+bias)); 1 = outf = c+bias+res; 3 = outf += scale*c
__global__ __launch_bounds__(256, 2)
void gemm_bt(const short* __restrict__ A, int lda, const short* __restrict__ B, int ldb,
             int K, int mode, const float* __restrict__ bias,
             const float* __restrict__ res, int ldres,
             float* __restrict__ outf, short* __restrict__ outb, int ldo, float scale)
{
  __shared__ __align__(16) short As[64 * 64];
  __shared__ __align__(16) short Bs[128 * 64];
  const int tid = threadIdx.x;
  const int lane = tid & 63, wave = tid >> 6;
  const int wm = wave >> 1, wn = wave & 1;
  const int l16 = lane & 15, q = lane >> 4;
  const size_t i0 = (size_t)blockIdx.y * 64;
  const int n0 = blockIdx.x * 128;
  fx4 acc[2][4] = {};

  for (int k0 = 0; k0 < K; k0 += 64){
    #pragma unroll
    for (int inst = 0; inst < 2; ++inst){              // A tile 64x64 = 8KB
      int ch = inst * 256 + tid;
      int r = ch >> 3, pc = ch & 7;
      int colc = (pc ^ (r & 7)) * 8;
      g2l16(A + (i0 + r) * (size_t)lda + k0 + colc, As + ch * 8);
    }
    #pragma unroll
    for (int inst = 0; inst < 4; ++inst){              // B tile 128x64 = 16KB
      int ch = inst * 256 + tid;
      int r = ch >> 3, pc = ch & 7;
      int colc = (pc ^ (r & 7)) * 8;
      g2l16(B + (size_t)(n0 + r) * (size_t)ldb + k0 + colc, Bs + ch * 8);
    }
    __syncthreads();
    #pragma unroll
    for (int ks = 0; ks < 2; ++ks){
      int k8 = ks * 4 + q;
      bf16x8 af[2], bfr[4];
      #pragma unroll
      for (int mi = 0; mi < 2; ++mi){
        int r = wm * 32 + mi * 16 + l16;
        af[mi] = *(const bf16x8*)(As + r * 64 + ((k8 ^ (r & 7)) << 3));
      }
      #pragma unroll
      for (int ni = 0; ni < 4; ++ni){
        int r = wn * 64 + ni * 16 + l16;
        bfr[ni] = *(const bf16x8*)(Bs + r * 64 + ((k8 ^ (r & 7)) << 3));
      }
      #pragma unroll
      for (int mi = 0; mi < 2; ++mi)
        #pragma unroll
        for (int ni = 0; ni < 4; ++ni)
          acc[mi][ni] = __builtin_amdgcn_mfma_f32_16x16x32_bf16(af[mi], bfr[ni], acc[mi][ni], 0, 0, 0);
    }
    __syncthreads();
  }
  // epilogue: C frag layout col=lane&15 (n), row=q*4+r (m)  [HW-verified R1]
  #pragma unroll
  for (int mi = 0; mi < 2; ++mi){
    #pragma unroll
    for (int ni = 0; ni < 4; ++ni){
      int n = n0 + wn * 64 + ni * 16 + l16;
      float b = bias ? bias[n] : 0.0f;
      #pragma unroll
      for (int r = 0; r < 4; ++r){
        size_t m = i0 + wm * 32 + mi * 16 + q * 4 + r;
        float v = acc[mi][ni][r];
        size_t o = m * (size_t)ldo + n;
        if (mode == 0)      outb[o] = f2bf(tanh_fast(v + b));
        else if (mode == 1) outf[o] = v + b + res[m * (size_t)ldres + n];
        else                outf[o] += v * scale;   // mode 3
      }
    }
  }
}

// ---------------- fused attention, register-resident P, dup=1 wave split ----------------
// 256 threads, 4 waves = 4 DISTINCT 16-row i-slices (IT=64); each wave covers the FULL
// GT g-range -> transform computed exactly once per (i,j) within the block.
// MODE 0 (smooth): P_ij = E_j*exp(-sqrt(max(sq_i+sq_j-2*enc_i.enc_j,0)));
//                  OUT[i][g] = (P@V)/rowsum(P), dual f32 write. V = denoisedT (permuted).
// MODE 1 (heads):  P_ij = sigmoid(Ah_i.enc_j); OUT bf16 [i][z*GG+g]. V = smoothedT (perm).
// j-loop chunks of CH; LDS V double-buffered (2*GT*CH*2 B = 64 KB) -> one barrier/chunk;
// DMA(n+1) + transform(n+1) VALU share the region with PV(n) MFMAs so the scheduler
// interleaves vector-pipe and matrix-pipe work. P never touches memory.
template<int GT, int CH, int MODE>
__global__ __launch_bounds__(256, 2)
void attn_reg(const short* __restrict__ encA, const short* __restrict__ encJ,
              const short* __restrict__ VTp,
              const float* __restrict__ sq, const float* __restrict__ E,
              float* __restrict__ out0, float* __restrict__ out1,
              short* __restrict__ outb, int ldo)
{
  constexpr int NG  = GT / 16;          // g-tiles per wave
  constexpr int KS  = CH / 32;          // MFMA k-steps per chunk
  constexpr int CPR = CH / 8;           // 16B chunks per LDS row
  constexpr int HB  = GT * CH;          // shorts per LDS buffer
  __shared__ __align__(16) short Vl[2 * HB];
  const int tid = threadIdx.x, lane = tid & 63, wave = tid >> 6;
  const int l16 = lane & 15, q = lane >> 4;
  const int i0 = blockIdx.y * 64 + wave * 16;
  const int g0 = blockIdx.x * GT;
  const short* Ai = encA + (size_t)blockIdx.z * NC * 32;

  const bf16x8 bi = *(const bf16x8*)(Ai + (size_t)(i0 + l16) * 32 + q * 8);
  float sqi = 0.f, lacc = 0.f;
  if (MODE == 0) sqi = sq[i0 + l16];
  fx4 acc[NG] = {};
  uint4v bP[KS], bPn[KS];

  auto stage = [&](int jc, int buf){
    #pragma unroll
    for (int inst = 0; inst < HB / 2048; ++inst){
      int ch = inst * 256 + tid;
      int r = ch / CPR, pc = ch % CPR;
      int colc = (pc ^ (r & (CPR - 1))) * 8;
      g2l16(VTp + (size_t)(g0 + r) * NC + jc + colc, Vl + buf * HB + ch * 8);
    }
  };
  auto transform = [&](int jb, uint4v* o){
    #pragma unroll
    for (int ks = 0; ks < KS; ++ks){
      uint32_t dw[4];
      #pragma unroll
      for (int jt = 0; jt < 2; ++jt){
        int j0 = jb + ks * 32 + jt * 16;
        bf16x8 aj = *(const bf16x8*)(encJ + (size_t)(j0 + l16) * 32 + q * 8);
        float4 sqj = {}, Ej = {};
        if (MODE == 0){
          sqj = *(const float4*)(sq + j0 + q * 4);
          Ej  = *(const float4*)(E  + j0 + q * 4);
        }
        fx4 c = {};
        c = __builtin_amdgcn_mfma_f32_16x16x32_bf16(aj, bi, c, 0, 0, 0);
        float pv[4];
        #pragma unroll
        for (int r = 0; r < 4; ++r){
          float dot = c[r];
          if (MODE == 0){
            float d2 = fmaxf(sqi + ((const float*)&sqj)[r] - 2.0f * dot, 0.0f);
            float p = ((const float*)&Ej)[r] * __expf(-fast_sqrt(d2));
            lacc += p;
            pv[r] = p;
          } else {
            pv[r] = fast_rcp(1.0f + __expf(-dot));
          }
        }
        dw[jt * 2]     = pack_bf(pv[0], pv[1]);
        dw[jt * 2 + 1] = pack_bf(pv[2], pv[3]);
      }
      uint4v u = { dw[0], dw[1], dw[2], dw[3] };
      o[ks] = u;
    }
  };
  auto pv_step = [&](int buf){
    #pragma unroll
    for (int ks = 0; ks < KS; ++ks){
      int k8 = ks * 4 + q;
      #pragma unroll
      for (int gt = 0; gt < NG; ++gt){
        int rr = gt * 16 + l16;
        bf16x8 av = *(const bf16x8*)(Vl + buf * HB + rr * CH + ((k8 ^ (rr & (CPR - 1))) << 3));
        acc[gt] = __builtin_amdgcn_mfma_f32_16x16x32_bf16(
            av, *(const bf16x8*)&bP[ks], acc[gt], 0, 0, 0);
      }
    }
  };

  stage(0, 0);
  transform(0, bP);
  __syncthreads();                       // DMA(0) drained (vmcnt before barrier)
  for (int jc = 0; jc < NC; jc += CH){
    int buf = (jc / CH) & 1;
    int nxt = jc + CH;
    if (nxt < NC){
      stage(nxt, buf ^ 1);               // DMA into other buffer (safe: barrier'd last iter)
      transform(nxt, bPn);               // VALU — interleaves with PV MFMAs below
    }
    pv_step(buf);
    #pragma unroll
    for (int ks = 0; ks < KS; ++ks) bP[ks] = bPn[ks];
    if (nxt < NC) __syncthreads();       // PV(jc) reads done + DMA(nxt) drained
  }

  // epilogue: D frag col = i (l16), row = g (q*4+r)
  if (MODE == 0){
    float v = lacc;                      // reduce over the 4 q-lanes of this i-row
    v += __shfl_xor(v, 16);
    v += __shfl_xor(v, 32);
    float inv = fast_rcp(v);
    #pragma unroll
    for (int gt = 0; gt < NG; ++gt){
      int g = g0 + gt * 16 + q * 4;
      float4 o;
      o.x = acc[gt][0] * inv; o.y = acc[gt][1] * inv;
      o.z = acc[gt][2] * inv; o.w = acc[gt][3] * inv;
      size_t off = (size_t)(i0 + l16) * GG + g;
      *(float4*)(out0 + off) = o;
      *(float4*)(out1 + off) = o;
    }
  } else {
    #pragma unroll
    for (int gt = 0; gt < NG; ++gt){
      int g = g0 + gt * 16 + q * 4;
      uint2 u;
      u.x = pack_bf(acc[gt][0], acc[gt][1]);
      u.y = pack_bf(acc[gt][2], acc[gt][3]);
      *(uint2*)(outb + (size_t)(i0 + l16) * ldo + (size_t)blockIdx.z * GG + g) = u;
    }
  }
}

// ---------------- small MLP tails ----------------
// enc = Hc[:,0:256] @ eW2 + eb2 (bf16-rounded), sq = |enc|^2, Ah[h] = enc @ T[h]
__global__ void embed2_kernel(const short* __restrict__ H2, int lda,
                              const float* __restrict__ eW2,
                              const float* __restrict__ eb2, const float* __restrict__ T4,
                              short* __restrict__ encb, float* __restrict__ sq,
                              short* __restrict__ Ah)
{
  __shared__ float encS[8][32];
  int d = threadIdx.x & 31, cl = threadIdx.x >> 5;
  size_t c = (size_t)blockIdx.x * 8 + cl;
  float s = eb2[d];
  const short* hrow = H2 + c * lda;
  for (int k = 0; k < 256; ++k) s += bf2f(hrow[k]) * eW2[k * 32 + d];
  short eb = f2bf(s);
  encb[c * 32 + d] = eb;
  encS[cl][d] = bf2f(eb);
  __syncthreads();
  if (d == 0){
    float t = 0;
    for (int k = 0; k < 32; ++k) t += encS[cl][k] * encS[cl][k];
    sq[c] = t;
  }
  #pragma unroll
  for (int h = 0; h < 4; ++h){
    float a = 0;
    const float* T = T4 + h * 1024;
    for (int k = 0; k < 32; ++k) a += encS[cl][k] * T[k * 32 + d];
    Ah[(size_t)h * NC * 32 + c * 32 + d] = f2bf(a);
  }
}

// E[c] = exp(Hq[c,:64] . qW2 + qb2)   (tanh already applied by GEMM1)
__global__ void qtail_kernel(const short* __restrict__ Hq, int lda,
                             const float* __restrict__ qW2, const float* __restrict__ qb2,
                             float* __restrict__ E)
{
  int j = threadIdx.x & 63, cl = threadIdx.x >> 6;
  size_t c = (size_t)blockIdx.x * 4 + cl;
  float t = bf2f(Hq[c * lda + j]) * qW2[j];
  #pragma unroll
  for (int o = 32; o >= 1; o >>= 1) t += __shfl_xor(t, o);
  if (j == 0) E[c] = __expf(t + qb2[0]);
}

// ---------------- host ----------------
extern "C" void kernel_launch(void* const* d_in, const int* in_sizes, int n_in,
                              void* d_out, int out_size, void* d_ws, size_t ws_size,
                              hipStream_t stream)
{
  const float* raw = (const float*)d_in[0];
  const float* dW1 = (const float*)d_in[1];
  const float* db1 = (const float*)d_in[2];
  const float* dW2 = (const float*)d_in[3];
  const float* db2 = (const float*)d_in[4];
  const float* eW1 = (const float*)d_in[5];
  const float* eb1 = (const float*)d_in[6];
  const float* eW2 = (const float*)d_in[7];
  const float* eb2 = (const float*)d_in[8];
  const float* qW1 = (const float*)d_in[9];
  const float* qb1 = (const float*)d_in[10];
  const float* qW2 = (const float*)d_in[11];
  const float* qb2 = (const float*)d_in[12];
  const float* Tr  = (const float*)d_in[13];
  const float* Gr  = (const float*)d_in[14];

  float* outD = (float*)d_out;                    // denoised [8192][512]
  float* outS = outD + (size_t)NC * GG;           // smoothed
  float* outF = outS + (size_t)NC * GG;           // final

  char* ws = (char*)d_ws;
  size_t off = 0;
  auto take = [&](size_t bytes) -> char* {
    char* p = ws + off; off += (bytes + 255) & ~(size_t)255; return p;
  };
  short* Xb    = (short*)take((size_t)NC * GG * 2);       // raw bf16
  short* WcatT = (short*)take((size_t)896 * 512 * 2);     // [dW1|eW1|qW1]^T, rows 832..895 pad
  short* dW2T  = (short*)take((size_t)512 * 512 * 2);
  short* GTc   = (short*)take((size_t)512 * 2048 * 2);    // gene_responses^T concat
  float* bcat  = (float*)take((size_t)896 * 4);
  short* Hcat  = (short*)take((size_t)NC * 896 * 2);      // tanh hidden concat [cell][896]
  short* denTp = (short*)take((size_t)GG * NC * 2);       // denoised^T, k-permuted
  short* smoTp = (short*)take((size_t)GG * NC * 2);       // smoothed^T, k-permuted
  short* encb  = (short*)take((size_t)NC * 32 * 2);
  short* Ahb   = (short*)take((size_t)4 * NC * 32 * 2);
  float* sqv   = (float*)take((size_t)NC * 4);
  float* Ev    = (float*)take((size_t)NC * 4);
  short* Ucat  = (short*)take((size_t)NC * 2048 * 2);     // head outputs concat

  dim3 b256(256);
  // ---- casts / transposed weights / bias concat ----
  cast_f32_bf16<<<dim3((NC * GG) / 1024), b256, 0, stream>>>(raw, Xb, NC * GG);
  transpose_cast<<<dim3(16, 16), b256, 0, stream>>>(dW1, WcatT, 512, 512, 512, 0, 0);
  transpose_cast<<<dim3(8, 16),  b256, 0, stream>>>(eW1, WcatT + 512 * 512, 512, 256, 512, 0, 0);
  transpose_cast<<<dim3(2, 16),  b256, 0, stream>>>(qW1, WcatT + 768 * 512, 512, 64, 512, 0, 0);
  transpose_cast<<<dim3(16, 16), b256, 0, stream>>>(dW2, dW2T, 512, 512, 512, 0, 0);
  for (int h = 0; h < 4; ++h)
    transpose_cast<<<dim3(16, 16), b256, 0, stream>>>(Gr + (size_t)h * 512 * 512,
                                                      GTc, 512, 512, 2048, h * 512, 0);
  fill_bias<<<dim3(4), b256, 0, stream>>>(db1, eb1, qb1, bcat);
  // ---- fused first layer: Hcat = tanh(X @ [dW1|eW1|qW1] + bcat)  (N=896) ----
  gemm_bt<<<dim3(7, 128), b256, 0, stream>>>(Xb, 512, WcatT, 512, 512, 0, bcat,
                                             (const float*)nullptr, 0,
                                             (float*)nullptr, Hcat, 896, 1.0f);
  // ---- denoise layer 2: outD = Hcat[:,0:512] @ dW2 + db2 + raw ----
  gemm_bt<<<dim3(4, 128), b256, 0, stream>>>(Hcat, 896, dW2T, 512, 512, 1, db2,
                                             raw, 512, outD, (short*)nullptr, 512, 1.0f);
  transpose_cast<<<dim3(16, 256), b256, 0, stream>>>(outD, denTp, NC, 512, NC, 0, 1);
  // ---- embed tail + quality tail ----
  embed2_kernel<<<dim3(NC / 8), b256, 0, stream>>>(Hcat + 512, 896, eW2, eb2, Tr,
                                                   encb, sqv, Ahb);
  qtail_kernel<<<dim3(NC / 4), b256, 0, stream>>>(Hcat + 768, 896, qW2, qb2, Ev);
  // ---- fused smooth: outS = outF = softmax-weighted avg of denoised (dup=2) ----
  attn_reg<256, 64, 0><<<dim3(2, 128, 1), b256, 0, stream>>>(
      encb, encb, denTp, sqv, Ev, outS, outF, (short*)nullptr, 0);
  transpose_cast<<<dim3(16, 256), b256, 0, stream>>>(outS, smoTp, NC, 512, NC, 0, 1);
  // ---- fused heads: Ucat[:, h*512:] = sigmoid(Ah_h enc^T) @ smoothed (dup=1) ----
  attn_reg<512, 32, 1><<<dim3(1, 128, 4), b256, 0, stream>>>(
      Ahb, encb, smoTp, (const float*)nullptr, (const float*)nullptr,
      (float*)nullptr, (float*)nullptr, Ucat, 2048);
  // ---- final += (Ucat @ GTcat^T) / N   (single K=2048 GEMM) ----
  gemm_bt<<<dim3(4, 128), b256, 0, stream>>>(Ucat, 2048, GTc, 2048, 2048,
                                             3, (const float*)nullptr,
                                             (const float*)nullptr, 0,
                                             outF, (short*)nullptr, 512, 1.0f / NC);
}